// Round 12
// baseline (39.621 us; speedup 1.0000x reference)
//
#include <hip/hip_runtime.h>
#include <math.h>

namespace {
typedef float v2f __attribute__((ext_vector_type(2)));

constexpr int B = 16, CH = 4, H = 512, W = 512, HID = 8;
constexpr int STRIP  = 16;           // rows per block
constexpr int SLOT_F = CH * W;       // one full row, all channels = 8 KB
constexpr int NSLOT  = 8;            // 64 KB ring -> 2 blocks/CU

static __device__ __forceinline__ v2f splat(float f){ v2f r; r.x=f; r.y=f; return r; }

// Block = 512 thr = 8 waves; per pair-iter waves 0-3 compute row r, 4-7 row r+1.
// Rows march through an 8-slot LDS ring fed by global_load_lds, prefetched
// 2 pair-iters (~4 rows) ahead with counted vmcnt (never drained mid-loop).
// vs r8: nontemporal (cache-bypass) stores for out, nt load for noise —
// keep L2/L3 exclusively for the reused x rows. (ext_vector types: the
// builtin rejects HIP_vector_type classes.)
__global__ __launch_bounds__(512) void ca_kernel(
    const float* __restrict__ x,      // [16,4,512,512]
    const float* __restrict__ w1w,    // [8,16]
    const float* __restrict__ w1b,    // [8]
    const float* __restrict__ w2w,    // [4,8]
    const float* __restrict__ noise,  // [16,1,512,512]
    float* __restrict__ out)          // [16,4,512,512]
{
    __shared__ float smem[NSLOT * SLOT_F];

    const int blk  = blockIdx.x;             // 512 blocks
    const int b    = blk >> 5;               // image
    const int hs   = (blk & 31) * STRIP;     // strip start row
    const int tid  = threadIdx.x;
    const int wv   = tid >> 6;               // wave 0..7
    const int lane = tid & 63;
    const int rsel = tid >> 8;               // 0: row r, 1: row r+1
    const int w0   = (tid & 255) << 1;       // 2 consecutive columns
    const int pl   = (w0 - 2) & (W - 1);     // left neighbor pair (wraps in-slot)
    const int pr   = (w0 + 2) & (W - 1);     // right neighbor pair

    const float* xb = x + (size_t)b * CH * H * W;
    const int dch   = wv >> 1;               // DMA: wave -> (channel, half-row)
    const int dhalf = wv & 1;

    // stage one full row (4ch, 8KB): each wave one 1KB global_load_lds chunk
    auto dma = [&](int q) {
        const int row  = q & (H - 1);
        const int slot = (q - hs + 1) & (NSLOT - 1);
        const float* g = xb + ((size_t)dch * H + row) * W + dhalf * 256 + lane * 4;
        const float* l = &smem[slot * SLOT_F + dch * W + dhalf * 256]; // wave-uniform base
        __builtin_amdgcn_global_load_lds(
            (const __attribute__((address_space(1))) void*)g,
            (__attribute__((address_space(3))) void*)l, 16, 0, 0);
    };

    // prologue: rows hs-1 .. hs+4 (6 loads/wave)
    dma(hs - 1); dma(hs); dma(hs + 1); dma(hs + 2); dma(hs + 3); dma(hs + 4);

    auto step = [&](int k) {
        __builtin_amdgcn_s_barrier();
        if (k <= 5) { dma(hs + 2 * k + 5); dma(hs + 2 * k + 6); }  // 2 iters ahead

        const int r  = hs + 2 * k + rsel;
        const int sT = (2 * k + rsel)     & 7;   // slot of row r-1
        const int sM = (2 * k + rsel + 1) & 7;   // row r
        const int sB = (2 * k + rsel + 2) & 7;   // row r+1

        v2f hpre[HID];
#pragma unroll
        for (int o = 0; o < HID; ++o) hpre[o] = splat(w1b[o]);
        v2f xcv[CH];

#pragma unroll
        for (int ch = 0; ch < CH; ++ch) {
            const float* T  = &smem[sT * SLOT_F + ch * W];
            const float* M  = &smem[sM * SLOT_F + ch * W];
            const float* Bt = &smem[sB * SLOT_F + ch * W];
            const float2 t2 = *(const float2*)&T[w0];
            const float2 tl = *(const float2*)&T[pl];
            const float2 tr = *(const float2*)&T[pr];
            const float2 m2 = *(const float2*)&M[w0];
            const float2 ml = *(const float2*)&M[pl];
            const float2 mr = *(const float2*)&M[pr];
            const float2 b2 = *(const float2*)&Bt[w0];
            const float2 bl = *(const float2*)&Bt[pl];
            const float2 br = *(const float2*)&Bt[pr];

            v2f tv; tv.x = t2.x; tv.y = t2.y;
            v2f mv; mv.x = m2.x; mv.y = m2.y;
            v2f bv; bv.x = b2.x; bv.y = b2.y;
            const v2f sP = __builtin_elementwise_fma(splat(2.f), mv, tv + bv);
            const v2f dP = bv - tv;
            const float sL = fmaf(2.f, ml.y, tl.y + bl.y);   // col w0-1
            const float dL = bl.y - tl.y;
            const float sR = fmaf(2.f, mr.x, tr.x + br.x);   // col w0+2
            const float dR = br.x - tr.x;

            v2f sprev; sprev.x = sL;   sprev.y = sP.x;
            v2f snext; snext.x = sP.y; snext.y = sR;
            v2f dprev; dprev.x = dL;   dprev.y = dP.x;
            v2f dnext; dnext.x = dP.y; dnext.y = dR;

            const v2f id = mv;
            const v2f sx = snext - sprev;
            const v2f sy = __builtin_elementwise_fma(splat(2.f), dP, dprev + dnext);
            const v2f lp = __builtin_elementwise_fma(splat(-16.f), mv,
                             __builtin_elementwise_fma(splat(2.f), sP, sprev + snext));
            xcv[ch] = mv;                      // residual straight from LDS
#pragma unroll
            for (int o = 0; o < HID; ++o) {
                const float* w1r = w1w + o * 16 + ch * 4;   // scalar (K$) loads
                v2f a = hpre[o];
                a = __builtin_elementwise_fma(id, splat(w1r[0]), a);
                a = __builtin_elementwise_fma(sx, splat(w1r[1]), a);
                a = __builtin_elementwise_fma(sy, splat(w1r[2]), a);
                a = __builtin_elementwise_fma(lp, splat(w1r[3]), a);
                hpre[o] = a;
            }
        }

#pragma unroll
        for (int o = 0; o < HID; ++o)
            hpre[o] = __builtin_elementwise_max(hpre[o], splat(0.f));

        const v2f nz = __builtin_nontemporal_load(
            (const v2f*)&noise[((size_t)b * H + r) * W + w0]);
        v2f mk; mk.x = floorf(nz.x + 0.5f); mk.y = floorf(nz.y + 0.5f);

#pragma unroll
        for (int ch = 0; ch < CH; ++ch) {
            v2f dd = splat(0.f);
#pragma unroll
            for (int o = 0; o < HID; ++o)
                dd = __builtin_elementwise_fma(hpre[o], splat(w2w[ch * HID + o]), dd);
            const v2f ov = __builtin_elementwise_fma(dd, mk, xcv[ch]);
            __builtin_nontemporal_store(
                ov, (v2f*)&out[((size_t)(b * CH + ch) * H + r) * W + w0]);
        }
    };

    // counted waits, derived counting LOAD-class ops only (dma+noise) so the
    // schedule is conservative under either vmcnt-store-counting semantics.
#define WAITVM(n) asm volatile("s_waitcnt vmcnt(" #n ")" ::: "memory")
    WAITVM(2); step(0);
    WAITVM(3); step(1);
    WAITVM(4); step(2);
    WAITVM(4); step(3);
    WAITVM(4); step(4);
    WAITVM(4); step(5);
    WAITVM(4); step(6);
    WAITVM(2); step(7);
#undef WAITVM
}
} // namespace

extern "C" void kernel_launch(void* const* d_in, const int* in_sizes, int n_in,
                              void* d_out, int out_size, void* d_ws, size_t ws_size,
                              hipStream_t stream) {
    const float* x     = (const float*)d_in[0];
    const float* w1w   = (const float*)d_in[1];
    const float* w1b   = (const float*)d_in[2];
    const float* w2w   = (const float*)d_in[3];
    const float* noise = (const float*)d_in[4];
    float* out = (float*)d_out;

    const int blocks = B * (H / STRIP);   // 512 = 2 blocks/CU, all resident
    ca_kernel<<<blocks, 512, 0, stream>>>(x, w1w, w1b, w2w, noise, out);
}

// Round 13
// 35.066 us; speedup vs baseline: 1.1299x; 1.1299x over previous
//
#include <hip/hip_runtime.h>
#include <math.h>

namespace {
typedef float v2f __attribute__((ext_vector_type(2)));

constexpr int B = 16, CH = 4, H = 512, W = 512, HID = 8;
constexpr int STRIP  = 16;           // rows per block
constexpr int SLOT_F = CH * W;       // one full row, all channels = 8 KB
constexpr int NSLOT  = 8;            // 64 KB ring -> 2 blocks/CU

static __device__ __forceinline__ v2f splat(float f){ v2f r; r.x=f; r.y=f; return r; }

// Block = 512 thr = 8 waves; per pair-iter waves 0-3 compute row r, 4-7 row r+1.
// Rows march through an 8-slot LDS ring fed by global_load_lds, prefetched
// 2 pair-iters (~4 rows) ahead with counted vmcnt (never drained mid-loop).
// Best-measured configuration (r8: 34.85 µs, ~6% above the empirical
// ~33 µs service-rate floor for this op's mixed read/write stream).
__global__ __launch_bounds__(512) void ca_kernel(
    const float* __restrict__ x,      // [16,4,512,512]
    const float* __restrict__ w1w,    // [8,16]
    const float* __restrict__ w1b,    // [8]
    const float* __restrict__ w2w,    // [4,8]
    const float* __restrict__ noise,  // [16,1,512,512]
    float* __restrict__ out)          // [16,4,512,512]
{
    __shared__ float smem[NSLOT * SLOT_F];

    const int blk  = blockIdx.x;             // 512 blocks
    const int b    = blk >> 5;               // image
    const int hs   = (blk & 31) * STRIP;     // strip start row
    const int tid  = threadIdx.x;
    const int wv   = tid >> 6;               // wave 0..7
    const int lane = tid & 63;
    const int rsel = tid >> 8;               // 0: row r, 1: row r+1
    const int w0   = (tid & 255) << 1;       // 2 consecutive columns
    const int pl   = (w0 - 2) & (W - 1);     // left neighbor pair (wraps in-slot)
    const int pr   = (w0 + 2) & (W - 1);     // right neighbor pair

    const float* xb = x + (size_t)b * CH * H * W;
    const int dch   = wv >> 1;               // DMA: wave -> (channel, half-row)
    const int dhalf = wv & 1;

    // stage one full row (4ch, 8KB): each wave one 1KB global_load_lds chunk
    auto dma = [&](int q) {
        const int row  = q & (H - 1);
        const int slot = (q - hs + 1) & (NSLOT - 1);
        const float* g = xb + ((size_t)dch * H + row) * W + dhalf * 256 + lane * 4;
        const float* l = &smem[slot * SLOT_F + dch * W + dhalf * 256]; // wave-uniform base
        __builtin_amdgcn_global_load_lds(
            (const __attribute__((address_space(1))) void*)g,
            (__attribute__((address_space(3))) void*)l, 16, 0, 0);
    };

    // prologue: rows hs-1 .. hs+4 (6 loads/wave)
    dma(hs - 1); dma(hs); dma(hs + 1); dma(hs + 2); dma(hs + 3); dma(hs + 4);

    auto step = [&](int k) {
        __builtin_amdgcn_s_barrier();
        if (k <= 5) { dma(hs + 2 * k + 5); dma(hs + 2 * k + 6); }  // 2 iters ahead

        const int r  = hs + 2 * k + rsel;
        const int sT = (2 * k + rsel)     & 7;   // slot of row r-1
        const int sM = (2 * k + rsel + 1) & 7;   // row r
        const int sB = (2 * k + rsel + 2) & 7;   // row r+1

        v2f hpre[HID];
#pragma unroll
        for (int o = 0; o < HID; ++o) hpre[o] = splat(w1b[o]);
        v2f xcv[CH];

#pragma unroll
        for (int ch = 0; ch < CH; ++ch) {
            const float* T  = &smem[sT * SLOT_F + ch * W];
            const float* M  = &smem[sM * SLOT_F + ch * W];
            const float* Bt = &smem[sB * SLOT_F + ch * W];
            const float2 t2 = *(const float2*)&T[w0];
            const float2 tl = *(const float2*)&T[pl];
            const float2 tr = *(const float2*)&T[pr];
            const float2 m2 = *(const float2*)&M[w0];
            const float2 ml = *(const float2*)&M[pl];
            const float2 mr = *(const float2*)&M[pr];
            const float2 b2 = *(const float2*)&Bt[w0];
            const float2 bl = *(const float2*)&Bt[pl];
            const float2 br = *(const float2*)&Bt[pr];

            v2f tv; tv.x = t2.x; tv.y = t2.y;
            v2f mv; mv.x = m2.x; mv.y = m2.y;
            v2f bv; bv.x = b2.x; bv.y = b2.y;
            const v2f sP = __builtin_elementwise_fma(splat(2.f), mv, tv + bv);
            const v2f dP = bv - tv;
            const float sL = fmaf(2.f, ml.y, tl.y + bl.y);   // col w0-1
            const float dL = bl.y - tl.y;
            const float sR = fmaf(2.f, mr.x, tr.x + br.x);   // col w0+2
            const float dR = br.x - tr.x;

            v2f sprev; sprev.x = sL;   sprev.y = sP.x;
            v2f snext; snext.x = sP.y; snext.y = sR;
            v2f dprev; dprev.x = dL;   dprev.y = dP.x;
            v2f dnext; dnext.x = dP.y; dnext.y = dR;

            const v2f id = mv;
            const v2f sx = snext - sprev;
            const v2f sy = __builtin_elementwise_fma(splat(2.f), dP, dprev + dnext);
            const v2f lp = __builtin_elementwise_fma(splat(-16.f), mv,
                             __builtin_elementwise_fma(splat(2.f), sP, sprev + snext));
            xcv[ch] = mv;                      // residual straight from LDS
#pragma unroll
            for (int o = 0; o < HID; ++o) {
                const float* w1r = w1w + o * 16 + ch * 4;   // scalar (K$) loads
                v2f a = hpre[o];
                a = __builtin_elementwise_fma(id, splat(w1r[0]), a);
                a = __builtin_elementwise_fma(sx, splat(w1r[1]), a);
                a = __builtin_elementwise_fma(sy, splat(w1r[2]), a);
                a = __builtin_elementwise_fma(lp, splat(w1r[3]), a);
                hpre[o] = a;
            }
        }

#pragma unroll
        for (int o = 0; o < HID; ++o)
            hpre[o] = __builtin_elementwise_max(hpre[o], splat(0.f));

        const float2 nz = *(const float2*)&noise[((size_t)b * H + r) * W + w0];
        v2f mk; mk.x = floorf(nz.x + 0.5f); mk.y = floorf(nz.y + 0.5f);

#pragma unroll
        for (int ch = 0; ch < CH; ++ch) {
            v2f dd = splat(0.f);
#pragma unroll
            for (int o = 0; o < HID; ++o)
                dd = __builtin_elementwise_fma(hpre[o], splat(w2w[ch * HID + o]), dd);
            const v2f ov = __builtin_elementwise_fma(dd, mk, xcv[ch]);
            float2 st; st.x = ov.x; st.y = ov.y;
            *(float2*)&out[((size_t)(b * CH + ch) * H + r) * W + w0] = st;
        }
    };

    // counted waits, derived counting LOAD-class ops only (dma+noise) so the
    // schedule is conservative under either vmcnt-store-counting semantics.
#define WAITVM(n) asm volatile("s_waitcnt vmcnt(" #n ")" ::: "memory")
    WAITVM(2); step(0);
    WAITVM(3); step(1);
    WAITVM(4); step(2);
    WAITVM(4); step(3);
    WAITVM(4); step(4);
    WAITVM(4); step(5);
    WAITVM(4); step(6);
    WAITVM(2); step(7);
#undef WAITVM
}
} // namespace

extern "C" void kernel_launch(void* const* d_in, const int* in_sizes, int n_in,
                              void* d_out, int out_size, void* d_ws, size_t ws_size,
                              hipStream_t stream) {
    const float* x     = (const float*)d_in[0];
    const float* w1w   = (const float*)d_in[1];
    const float* w1b   = (const float*)d_in[2];
    const float* w2w   = (const float*)d_in[3];
    const float* noise = (const float*)d_in[4];
    float* out = (float*)d_out;

    const int blocks = B * (H / STRIP);   // 512 = 2 blocks/CU, all resident
    ca_kernel<<<blocks, 512, 0, stream>>>(x, w1w, w1b, w2w, noise, out);
}